// Round 1
// baseline (197.561 us; speedup 1.0000x reference)
//
#include <hip/hip_runtime.h>
#include <stdint.h>

#define HH 56
#define WW 56
#define HW 3136
#define CC 128
#define BB 32
#define NPIX 100352        // B*H*W
#define NTOT 12845056      // B*C*H*W
#define EPSV 1e-5

struct alignas(16) U2 { unsigned long long lo, hi; };

// ---------------- K0: pack weights (sign bits along input channel) + zero accumulators
__global__ void k_pack_w(const float* __restrict__ w1, const float* __restrict__ w2,
                         U2* __restrict__ wb1, U2* __restrict__ wb2,
                         unsigned long long* __restrict__ sums1,
                         double* __restrict__ sums2) {
    int gtid = blockIdx.x * 256 + threadIdx.x;
    if (gtid < 256) sums1[gtid] = 0ull;
    else if (gtid < 512) sums2[gtid - 256] = 0.0;
    // 2 tensors * 128 o * 9 taps = 2304 jobs
    int tensor = gtid / 1152, rem = gtid % 1152;
    int o = rem / 9, tap = rem % 9;
    const float* w = tensor ? w2 : w1;
    unsigned long long lo = 0, hi = 0;
    for (int i = 0; i < 64; ++i)
        if (w[(o * 128 + i) * 9 + tap] > 0.f) lo |= 1ull << i;
    for (int i = 64; i < 128; ++i)
        if (w[(o * 128 + i) * 9 + tap] > 0.f) hi |= 1ull << (i - 64);
    U2 u; u.lo = lo; u.hi = hi;
    (tensor ? wb2 : wb1)[o * 9 + tap] = u;
}

// ---------------- K1: pack x sign bits; each thread does 4 consecutive pixels with float4 loads
__global__ void k_pack_x(const float* __restrict__ x, U2* __restrict__ xb) {
    int t = blockIdx.x * 256 + threadIdx.x;   // 25088 threads
    int pix0 = t * 4;
    int b = pix0 / HW, r = pix0 % HW;
    const float* base = x + (size_t)b * CC * HW + r;
    unsigned long long L0 = 0, L1 = 0, L2 = 0, L3 = 0;
    unsigned long long H0 = 0, H1 = 0, H2 = 0, H3 = 0;
#pragma unroll 8
    for (int c = 0; c < 64; ++c) {
        float4 v = *reinterpret_cast<const float4*>(base + (size_t)c * HW);
        unsigned long long m = 1ull << c;
        if (v.x > 0.f) L0 |= m;
        if (v.y > 0.f) L1 |= m;
        if (v.z > 0.f) L2 |= m;
        if (v.w > 0.f) L3 |= m;
    }
#pragma unroll 8
    for (int c = 64; c < 128; ++c) {
        float4 v = *reinterpret_cast<const float4*>(base + (size_t)c * HW);
        unsigned long long m = 1ull << (c - 64);
        if (v.x > 0.f) H0 |= m;
        if (v.y > 0.f) H1 |= m;
        if (v.z > 0.f) H2 |= m;
        if (v.w > 0.f) H3 |= m;
    }
    U2* o = xb + pix0;
    U2 u;
    u.lo = L0; u.hi = H0; o[0] = u;
    u.lo = L1; u.hi = H1; o[1] = u;
    u.lo = L2; u.hi = H2; o[2] = u;
    u.lo = L3; u.hi = H3; o[3] = u;
}

// ---------------- K2/K4: binary conv 3x3 via XNOR-popcount.
// grid = (392 pixel-blocks, 4 o-chunks of 32). RESID=1 adds residual and writes fp32.
template <int RESID>
__global__ __launch_bounds__(256)
void k_conv(const U2* __restrict__ xb, const U2* __restrict__ wb,
            short* __restrict__ yout,
            const float* __restrict__ resid, float* __restrict__ tout) {
    __shared__ U2 wl[288];        // 32 o * 9 taps
    __shared__ int corr[9 * 32];  // border-pattern correction per (pattern, oo)
    int tid = threadIdx.x;
    int o0 = blockIdx.y * 32;
    for (int j = tid; j < 288; j += 256) wl[j] = wb[o0 * 9 + j];
    __syncthreads();
    for (int j = tid; j < 288; j += 256) {
        int p = j / 32, oo = j % 32;
        int ph = p / 3, pw = p % 3;
        int c = 0;
#pragma unroll
        for (int t = 0; t < 9; ++t) {
            int kh = t / 3, kw = t % 3;
            bool inval = (ph == 1 && kh == 0) || (ph == 2 && kh == 2) ||
                         (pw == 1 && kw == 0) || (pw == 2 && kw == 2);
            if (inval) {
                U2 u = wl[oo * 9 + t];
                c += 128 - 2 * (int)(__popcll(u.lo) + __popcll(u.hi));
            }
        }
        corr[p * 32 + oo] = c;
    }
    __syncthreads();

    int pix = blockIdx.x * 256 + tid;
    int b = pix / HW, r = pix % HW;
    int h = r / WW, w = r % WW;
    int ph = (h == 0) ? 1 : ((h == HH - 1) ? 2 : 0);
    int pw = (w == 0) ? 1 : ((w == WW - 1) ? 2 : 0);
    int p = ph * 3 + pw;

    U2 xt[9];
#pragma unroll
    for (int t = 0; t < 9; ++t) {
        int kh = t / 3, kw = t % 3;
        bool inval = (ph == 1 && kh == 0) || (ph == 2 && kh == 2) ||
                     (pw == 1 && kw == 0) || (pw == 2 && kw == 2);
        if (inval) { xt[t].lo = 0ull; xt[t].hi = 0ull; }
        else        xt[t] = xb[pix + (kh - 1) * WW + (kw - 1)];
    }
    const int* corp = &corr[p * 32];
    size_t obase = (size_t)(b * CC + o0) * HW + r;
#pragma unroll 4
    for (int oo = 0; oo < 32; ++oo) {
        int S = 0;
#pragma unroll
        for (int t = 0; t < 9; ++t) {
            U2 wv = wl[oo * 9 + t];
            S += (int)(__popcll(xt[t].lo ^ wv.lo) + __popcll(xt[t].hi ^ wv.hi));
        }
        int y = 1152 - 2 * S - corp[oo];
        size_t idx = obase + (size_t)oo * HW;
        if (RESID) {
            tout[idx] = (float)y + resid[idx];
        } else {
            yout[idx] = (short)y;
        }
    }
}

// ---------------- K3: per-(b,o)-plane exact int sums of y1 -> global int64 accumulators
__global__ void k_stats_y1(const short* __restrict__ y1,
                           unsigned long long* __restrict__ sums1) {
    int plane = blockIdx.x;          // b*128 + o
    int o = plane & 127;
    const short* p = y1 + (size_t)plane * HW;
    int s = 0, ss = 0;
    for (int i = threadIdx.x; i < HW; i += 256) { int v = p[i]; s += v; ss += v * v; }
#pragma unroll
    for (int d = 1; d < 64; d <<= 1) { s += __shfl_xor(s, d); ss += __shfl_xor(ss, d); }
    __shared__ long long Ls[4], Lss[4];
    int wid = threadIdx.x >> 6, lane = threadIdx.x & 63;
    if (lane == 0) { Ls[wid] = s; Lss[wid] = ss; }
    __syncthreads();
    if (threadIdx.x == 0) {
        long long S = Ls[0] + Ls[1] + Ls[2] + Ls[3];
        long long SS = Lss[0] + Lss[1] + Lss[2] + Lss[3];
        atomicAdd(&sums1[o], (unsigned long long)S);
        atomicAdd(&sums1[128 + o], (unsigned long long)SS);
    }
}

// ---------------- K4: threshold y1 through BN1 sign and repack bits for conv2
__global__ void k_pack2(const short* __restrict__ y1,
                        const unsigned long long* __restrict__ sums1,
                        const float* __restrict__ gamma1, const float* __restrict__ beta1,
                        U2* __restrict__ xb2) {
    __shared__ double Ts[128];
    __shared__ int mode[128];   // +1: bit = y>T; -1: bit = y<T; 0: bit = cbit
    __shared__ int cbit[128];
    int tid = threadIdx.x;
    if (tid < 128) {
        long long S = (long long)sums1[tid];
        long long SS = (long long)sums1[128 + tid];
        double N = (double)NPIX;
        double mean = (double)S / N;
        double var = (double)SS / N - mean * mean;
        double rr = 1.0 / sqrt(var + EPSV);
        double s = (double)gamma1[tid] * rr;
        double bb = (double)beta1[tid] - mean * s;
        if (s > 0.0)      { mode[tid] = 1;  Ts[tid] = -bb / s; cbit[tid] = 0; }
        else if (s < 0.0) { mode[tid] = -1; Ts[tid] = -bb / s; cbit[tid] = 0; }
        else              { mode[tid] = 0;  Ts[tid] = 0.0;     cbit[tid] = (bb > 0.0); }
    }
    __syncthreads();
    int pix = blockIdx.x * 256 + tid;
    int b = pix / HW, r = pix % HW;
    const short* yp = y1 + (size_t)b * CC * HW + r;
    unsigned long long lo = 0, hi = 0;
    for (int o = 0; o < 64; ++o) {
        int y = yp[(size_t)o * HW];
        int m = mode[o];
        int bit = (m > 0) ? ((double)y > Ts[o]) : ((m < 0) ? ((double)y < Ts[o]) : cbit[o]);
        lo |= (unsigned long long)bit << o;
    }
    for (int o = 64; o < 128; ++o) {
        int y = yp[(size_t)o * HW];
        int m = mode[o];
        int bit = (m > 0) ? ((double)y > Ts[o]) : ((m < 0) ? ((double)y < Ts[o]) : cbit[o]);
        hi |= (unsigned long long)bit << (o - 64);
    }
    U2 u; u.lo = lo; u.hi = hi;
    xb2[pix] = u;
}

// ---------------- K6: per-plane double sums of t (= y2 + residual) for BN2
__global__ void k_stats_t(const float* __restrict__ t, double* __restrict__ sums2) {
    int plane = blockIdx.x;
    int o = plane & 127;
    const float* p = t + (size_t)plane * HW;
    double s = 0.0, ss = 0.0;
    for (int i = threadIdx.x; i < HW; i += 256) { double v = (double)p[i]; s += v; ss += v * v; }
#pragma unroll
    for (int d = 1; d < 64; d <<= 1) { s += __shfl_xor(s, d); ss += __shfl_xor(ss, d); }
    __shared__ double Ls[4], Lss[4];
    int wid = threadIdx.x >> 6, lane = threadIdx.x & 63;
    if (lane == 0) { Ls[wid] = s; Lss[wid] = ss; }
    __syncthreads();
    if (threadIdx.x == 0) {
        atomicAdd(&sums2[o], Ls[0] + Ls[1] + Ls[2] + Ls[3]);
        atomicAdd(&sums2[128 + o], Lss[0] + Lss[1] + Lss[2] + Lss[3]);
    }
}

// ---------------- K7: BN2 + hardtanh, in-place on d_out (float4)
__global__ void k_bn2(float* __restrict__ t, const double* __restrict__ sums2,
                      const float* __restrict__ gamma2, const float* __restrict__ beta2) {
    __shared__ float sA[128], bA[128];
    int tid = threadIdx.x;
    if (tid < 128) {
        double N = (double)NPIX;
        double mean = sums2[tid] / N;
        double var = sums2[128 + tid] / N - mean * mean;
        double rr = 1.0 / sqrt(var + EPSV);
        double s = (double)gamma2[tid] * rr;
        double bb = (double)beta2[tid] - mean * s;
        sA[tid] = (float)s; bA[tid] = (float)bb;
    }
    __syncthreads();
    size_t i4 = ((size_t)blockIdx.x * 256 + tid) * 4;
    int c = (int)((i4 / HW) & 127);
    float4 v = *reinterpret_cast<float4*>(t + i4);
    float s = sA[c], bb = bA[c];
    v.x = fminf(1.f, fmaxf(-1.f, v.x * s + bb));
    v.y = fminf(1.f, fmaxf(-1.f, v.y * s + bb));
    v.z = fminf(1.f, fmaxf(-1.f, v.z * s + bb));
    v.w = fminf(1.f, fmaxf(-1.f, v.w * s + bb));
    *reinterpret_cast<float4*>(t + i4) = v;
}

extern "C" void kernel_launch(void* const* d_in, const int* in_sizes, int n_in,
                              void* d_out, int out_size, void* d_ws, size_t ws_size,
                              hipStream_t stream) {
    const float* x      = (const float*)d_in[0];
    const float* w1     = (const float*)d_in[1];
    const float* w2     = (const float*)d_in[2];
    const float* gamma1 = (const float*)d_in[3];
    const float* beta1  = (const float*)d_in[4];
    const float* gamma2 = (const float*)d_in[5];
    const float* beta2  = (const float*)d_in[6];
    float* out = (float*)d_out;

    char* ws = (char*)d_ws;
    U2* wb1 = (U2*)ws;                 ws += 128 * 9 * sizeof(U2);   // 18432
    U2* wb2 = (U2*)ws;                 ws += 128 * 9 * sizeof(U2);   // 18432
    U2* xb  = (U2*)ws;                 ws += (size_t)NPIX * sizeof(U2);   // 1.6 MB
    U2* xb2 = (U2*)ws;                 ws += (size_t)NPIX * sizeof(U2);   // 1.6 MB
    short* y1 = (short*)ws;            ws += (size_t)NTOT * sizeof(short); // 25.7 MB
    unsigned long long* sums1 = (unsigned long long*)ws; ws += 256 * sizeof(unsigned long long);
    double* sums2 = (double*)ws;       ws += 256 * sizeof(double);

    k_pack_w<<<9, 256, 0, stream>>>(w1, w2, wb1, wb2, sums1, sums2);
    k_pack_x<<<98, 256, 0, stream>>>(x, xb);
    k_conv<0><<<dim3(392, 4), 256, 0, stream>>>(xb, wb1, y1, nullptr, nullptr);
    k_stats_y1<<<4096, 256, 0, stream>>>(y1, sums1);
    k_pack2<<<392, 256, 0, stream>>>(y1, sums1, gamma1, beta1, xb2);
    k_conv<1><<<dim3(392, 4), 256, 0, stream>>>(xb2, wb2, nullptr, x, out);
    k_stats_t<<<4096, 256, 0, stream>>>(out, sums2);
    k_bn2<<<12544, 256, 0, stream>>>(out, sums2, gamma2, beta2);
}

// Round 2
// 194.104 us; speedup vs baseline: 1.0178x; 1.0178x over previous
//
#include <hip/hip_runtime.h>
#include <stdint.h>

#define HH 56
#define WW 56
#define HW 3136
#define CC 128
#define BB 32
#define NPIX 100352        // B*H*W
#define NTOT 12845056      // B*C*H*W
#define EPSV 1e-5

struct alignas(16) U2 { unsigned long long lo, hi; };

__device__ inline int pc2(const U2& a, const U2& b) {
    return (int)(__popcll(a.lo ^ b.lo) + __popcll(a.hi ^ b.hi));
}

// ---------------- K0: pack weights (sign bits along input channel) + zero accumulators
__global__ void k_pack_w(const float* __restrict__ w1, const float* __restrict__ w2,
                         U2* __restrict__ wb1, U2* __restrict__ wb2,
                         unsigned long long* __restrict__ sums1,
                         double* __restrict__ sums2) {
    int gtid = blockIdx.x * 256 + threadIdx.x;
    if (gtid < 256) sums1[gtid] = 0ull;
    else if (gtid < 512) sums2[gtid - 256] = 0.0;
    int tensor = gtid / 1152, rem = gtid % 1152;
    int o = rem / 9, tap = rem % 9;
    const float* w = tensor ? w2 : w1;
    unsigned long long lo = 0, hi = 0;
    for (int i = 0; i < 64; ++i)
        if (w[(o * 128 + i) * 9 + tap] > 0.f) lo |= 1ull << i;
    for (int i = 64; i < 128; ++i)
        if (w[(o * 128 + i) * 9 + tap] > 0.f) hi |= 1ull << (i - 64);
    U2 u; u.lo = lo; u.hi = hi;
    (tensor ? wb2 : wb1)[o * 9 + tap] = u;
}

// ---------------- K1: pack x sign bits; each thread does 4 consecutive pixels with float4 loads
__global__ void k_pack_x(const float* __restrict__ x, U2* __restrict__ xb) {
    int t = blockIdx.x * 256 + threadIdx.x;   // 25088 threads
    int pix0 = t * 4;
    int b = pix0 / HW, r = pix0 % HW;
    const float* base = x + (size_t)b * CC * HW + r;
    unsigned long long L0 = 0, L1 = 0, L2 = 0, L3 = 0;
    unsigned long long H0 = 0, H1 = 0, H2 = 0, H3 = 0;
#pragma unroll 8
    for (int c = 0; c < 64; ++c) {
        float4 v = *reinterpret_cast<const float4*>(base + (size_t)c * HW);
        unsigned long long m = 1ull << c;
        if (v.x > 0.f) L0 |= m;
        if (v.y > 0.f) L1 |= m;
        if (v.z > 0.f) L2 |= m;
        if (v.w > 0.f) L3 |= m;
    }
#pragma unroll 8
    for (int c = 64; c < 128; ++c) {
        float4 v = *reinterpret_cast<const float4*>(base + (size_t)c * HW);
        unsigned long long m = 1ull << (c - 64);
        if (v.x > 0.f) H0 |= m;
        if (v.y > 0.f) H1 |= m;
        if (v.z > 0.f) H2 |= m;
        if (v.w > 0.f) H3 |= m;
    }
    U2* o = xb + pix0;
    U2 u;
    u.lo = L0; u.hi = H0; o[0] = u;
    u.lo = L1; u.hi = H1; o[1] = u;
    u.lo = L2; u.hi = H2; o[2] = u;
    u.lo = L3; u.hi = H3; o[3] = u;
}

// ---------------- K2/K4: binary conv 3x3, 4 pixels/thread, 16 o-channels/block-chunk.
// Fused per-channel stats: RESID=0 -> exact int sums of y; RESID=1 -> double sums of y+resid.
template <int RESID>
__global__ __launch_bounds__(256)
void k_conv4(const U2* __restrict__ xb, const U2* __restrict__ wb,
             short* __restrict__ yout,
             const float* __restrict__ resid, float* __restrict__ tout,
             unsigned long long* __restrict__ isums, double* __restrict__ dsums) {
    __shared__ U2 wl[144];            // 16 o * 9 taps
    __shared__ int corr[9 * 16];      // border correction per (pattern, oo)
    __shared__ double sW[4][16], ssW[4][16];
    __shared__ long long iW[4][16], iiW[4][16];
    int tid = threadIdx.x;
    int wid = tid >> 6, lane = tid & 63;
    int o0 = blockIdx.y * 16;
    if (tid < 144) wl[tid] = wb[o0 * 9 + tid];
    __syncthreads();
    if (tid < 144) {
        int p = tid / 16, oo = tid % 16;
        int ph = p / 3, pw = p % 3;
        int c = 0;
#pragma unroll
        for (int t = 0; t < 9; ++t) {
            int kh = t / 3, kw = t % 3;
            bool inval = (ph == 1 && kh == 0) || (ph == 2 && kh == 2) ||
                         (pw == 1 && kw == 0) || (pw == 2 && kw == 2);
            if (inval) {
                U2 u = wl[oo * 9 + t];
                c += 128 - 2 * (int)(__popcll(u.lo) + __popcll(u.hi));
            }
        }
        corr[p * 16 + oo] = c;
    }
    __syncthreads();

    int g = blockIdx.x * 256 + tid;   // 4-pixel group
    int pix0 = g * 4;
    int b = pix0 / HW, r = pix0 % HW;
    int h = r / WW, w0 = r % WW;      // w0 is a multiple of 4; groups never cross rows

    // load 3x6 halo of packed bits, zero-masked at borders
    U2 X[3][6];
    const U2* xbb = xb + (size_t)b * HW;
#pragma unroll
    for (int kh = 0; kh < 3; ++kh) {
        int row = h - 1 + kh;
        bool rv = (unsigned)row < HH;
        const U2* rp = xbb + row * WW;
#pragma unroll
        for (int c = 0; c < 6; ++c) {
            int col = w0 - 1 + c;
            if (rv && (unsigned)col < WW) X[kh][c] = rp[col];
            else { X[kh][c].lo = 0ull; X[kh][c].hi = 0ull; }
        }
    }

    int ph = (h == 0) ? 1 : ((h == HH - 1) ? 2 : 0);
    int pbase = ph * 3;
    int jspec = (w0 == 0) ? 0 : ((w0 == WW - 4) ? 3 : -1);
    int pspec = pbase + ((w0 == 0) ? 1 : 2);   // always a valid pattern index
    int pb16 = pbase * 16, ps16 = pspec * 16;

    size_t obase = (size_t)(b * CC + o0) * HW + r;
#pragma unroll 2
    for (int oo = 0; oo < 16; ++oo) {
        int S0 = 0, S1 = 0, S2 = 0, S3 = 0;
#pragma unroll
        for (int t = 0; t < 9; ++t) {
            int kh = t / 3, kw = t % 3;
            U2 wv = wl[oo * 9 + t];
            S0 += pc2(X[kh][kw + 0], wv);
            S1 += pc2(X[kh][kw + 1], wv);
            S2 += pc2(X[kh][kw + 2], wv);
            S3 += pc2(X[kh][kw + 3], wv);
        }
        int ci = corr[pb16 + oo];
        int cs = corr[ps16 + oo];
        int c0 = (jspec == 0) ? cs : ci;
        int c3 = (jspec == 3) ? cs : ci;
        int y0 = 1152 - 2 * S0 - c0;
        int y1v = 1152 - 2 * S1 - ci;
        int y2v = 1152 - 2 * S2 - ci;
        int y3v = 1152 - 2 * S3 - c3;
        size_t idx = obase + (size_t)oo * HW;
        if (RESID) {
            float4 rv4 = *reinterpret_cast<const float4*>(resid + idx);
            float4 tv;
            tv.x = (float)y0 + rv4.x;
            tv.y = (float)y1v + rv4.y;
            tv.z = (float)y2v + rv4.z;
            tv.w = (float)y3v + rv4.w;
            *reinterpret_cast<float4*>(tout + idx) = tv;
            double s = (double)tv.x + (double)tv.y + (double)tv.z + (double)tv.w;
            double ss = (double)tv.x * tv.x + (double)tv.y * tv.y +
                        (double)tv.z * tv.z + (double)tv.w * tv.w;
#pragma unroll
            for (int d = 1; d < 64; d <<= 1) { s += __shfl_xor(s, d); ss += __shfl_xor(ss, d); }
            if (lane == 0) { sW[wid][oo] = s; ssW[wid][oo] = ss; }
        } else {
            short4 sv;
            sv.x = (short)y0; sv.y = (short)y1v; sv.z = (short)y2v; sv.w = (short)y3v;
            *reinterpret_cast<short4*>(yout + idx) = sv;
            int s = y0 + y1v + y2v + y3v;
            int ss = y0 * y0 + y1v * y1v + y2v * y2v + y3v * y3v;
#pragma unroll
            for (int d = 1; d < 64; d <<= 1) { s += __shfl_xor(s, d); ss += __shfl_xor(ss, d); }
            if (lane == 0) { iW[wid][oo] = s; iiW[wid][oo] = ss; }
        }
    }
    __syncthreads();
    if (tid < 16) {
        if (RESID) {
            double s = sW[0][tid] + sW[1][tid] + sW[2][tid] + sW[3][tid];
            double ss = ssW[0][tid] + ssW[1][tid] + ssW[2][tid] + ssW[3][tid];
            atomicAdd(&dsums[o0 + tid], s);
            atomicAdd(&dsums[128 + o0 + tid], ss);
        } else {
            long long s = iW[0][tid] + iW[1][tid] + iW[2][tid] + iW[3][tid];
            long long ss = iiW[0][tid] + iiW[1][tid] + iiW[2][tid] + iiW[3][tid];
            atomicAdd(&isums[o0 + tid], (unsigned long long)s);
            atomicAdd(&isums[128 + o0 + tid], (unsigned long long)ss);
        }
    }
}

// ---------------- K3: threshold y1 through BN1 sign and repack bits for conv2 (2 px/thread)
__global__ void k_pack2(const short* __restrict__ y1,
                        const unsigned long long* __restrict__ sums1,
                        const float* __restrict__ gamma1, const float* __restrict__ beta1,
                        U2* __restrict__ xb2) {
    __shared__ int SG[128], TA[128];
    int tid = threadIdx.x;
    if (tid < 128) {
        long long S = (long long)sums1[tid];
        long long SS = (long long)sums1[128 + tid];
        double N = (double)NPIX;
        double mean = (double)S / N;
        double var = (double)SS / N - mean * mean;
        double rr = 1.0 / sqrt(var + EPSV);
        double s = (double)gamma1[tid] * rr;
        double bb = (double)beta1[tid] - mean * s;
        int sg, A;
        if (s > 0.0) {        // bit = y > T  <=>  y > floor(T)
            double f = floor(-bb / s);
            sg = 1; A = (int)fmax(-2000.0, fmin(2000.0, f));
        } else if (s < 0.0) { // bit = y < T  <=>  -y > -ceil(T)
            double cl = ceil(-bb / s);
            sg = -1; A = -(int)fmax(-2000.0, fmin(2000.0, cl));
        } else {
            sg = 0; A = (bb > 0.0) ? -1 : 0;   // 0 > -1 true ; 0 > 0 false
        }
        SG[tid] = sg; TA[tid] = A;
    }
    __syncthreads();
    int p2 = blockIdx.x * 256 + tid;   // 2-pixel group
    int pix0 = p2 * 2;
    int b = pix0 / HW, r = pix0 % HW;
    const short* yp = y1 + (size_t)b * CC * HW + r;
    unsigned long long lo0 = 0, hi0 = 0, lo1 = 0, hi1 = 0;
#pragma unroll 8
    for (int o = 0; o < 128; ++o) {
        int v = *reinterpret_cast<const int*>(yp + (size_t)o * HW);
        int ya = (int)(short)(v & 0xffff);
        int yb = v >> 16;
        int sg = SG[o], A = TA[o];
        unsigned long long ba = (unsigned long long)(ya * sg > A);
        unsigned long long bb = (unsigned long long)(yb * sg > A);
        if (o < 64) { lo0 |= ba << o;        lo1 |= bb << o; }
        else        { hi0 |= ba << (o - 64); hi1 |= bb << (o - 64); }
    }
    U2 u;
    u.lo = lo0; u.hi = hi0; xb2[pix0] = u;
    u.lo = lo1; u.hi = hi1; xb2[pix0 + 1] = u;
}

// ---------------- K5: BN2 + hardtanh, in-place on d_out (float4)
__global__ void k_bn2(float* __restrict__ t, const double* __restrict__ sums2,
                      const float* __restrict__ gamma2, const float* __restrict__ beta2) {
    __shared__ float sA[128], bA[128];
    int tid = threadIdx.x;
    if (tid < 128) {
        double N = (double)NPIX;
        double mean = sums2[tid] / N;
        double var = sums2[128 + tid] / N - mean * mean;
        double rr = 1.0 / sqrt(var + EPSV);
        double s = (double)gamma2[tid] * rr;
        double bb = (double)beta2[tid] - mean * s;
        sA[tid] = (float)s; bA[tid] = (float)bb;
    }
    __syncthreads();
    size_t i4 = ((size_t)blockIdx.x * 256 + tid) * 4;
    int c = (int)((i4 / HW) & 127);
    float4 v = *reinterpret_cast<float4*>(t + i4);
    float s = sA[c], bb = bA[c];
    v.x = fminf(1.f, fmaxf(-1.f, v.x * s + bb));
    v.y = fminf(1.f, fmaxf(-1.f, v.y * s + bb));
    v.z = fminf(1.f, fmaxf(-1.f, v.z * s + bb));
    v.w = fminf(1.f, fmaxf(-1.f, v.w * s + bb));
    *reinterpret_cast<float4*>(t + i4) = v;
}

extern "C" void kernel_launch(void* const* d_in, const int* in_sizes, int n_in,
                              void* d_out, int out_size, void* d_ws, size_t ws_size,
                              hipStream_t stream) {
    const float* x      = (const float*)d_in[0];
    const float* w1     = (const float*)d_in[1];
    const float* w2     = (const float*)d_in[2];
    const float* gamma1 = (const float*)d_in[3];
    const float* beta1  = (const float*)d_in[4];
    const float* gamma2 = (const float*)d_in[5];
    const float* beta2  = (const float*)d_in[6];
    float* out = (float*)d_out;

    char* ws = (char*)d_ws;
    U2* wb1 = (U2*)ws;                 ws += 128 * 9 * sizeof(U2);
    U2* wb2 = (U2*)ws;                 ws += 128 * 9 * sizeof(U2);
    U2* xb  = (U2*)ws;                 ws += (size_t)NPIX * sizeof(U2);
    U2* xb2 = (U2*)ws;                 ws += (size_t)NPIX * sizeof(U2);
    short* y1 = (short*)ws;            ws += (size_t)NTOT * sizeof(short);
    unsigned long long* sums1 = (unsigned long long*)ws; ws += 256 * sizeof(unsigned long long);
    double* sums2 = (double*)ws;       ws += 256 * sizeof(double);

    k_pack_w<<<9, 256, 0, stream>>>(w1, w2, wb1, wb2, sums1, sums2);
    k_pack_x<<<98, 256, 0, stream>>>(x, xb);
    k_conv4<0><<<dim3(98, 8), 256, 0, stream>>>(xb, wb1, y1, nullptr, nullptr, sums1, sums2);
    k_pack2<<<196, 256, 0, stream>>>(y1, sums1, gamma1, beta1, xb2);
    k_conv4<1><<<dim3(98, 8), 256, 0, stream>>>(xb2, wb2, nullptr, x, out, sums1, sums2);
    k_bn2<<<12544, 256, 0, stream>>>(out, sums2, gamma2, beta2);
}

// Round 3
// 188.479 us; speedup vs baseline: 1.0482x; 1.0298x over previous
//
#include <hip/hip_runtime.h>
#include <stdint.h>

#define HH 56
#define WW 56
#define HW 3136
#define CC 128
#define BB 32
#define NPIX 100352        // B*H*W
#define NTOT 12845056      // B*C*H*W
#define EPSV 1e-5

struct alignas(16) U2 { unsigned long long lo, hi; };

// ---------------- K0: pack weights (sign bits along input channel), write per-tap
// (128 - 2*popc(w)) values, and zero the stats accumulators.
__global__ void k_pack_w(const float* __restrict__ w1, const float* __restrict__ w2,
                         U2* __restrict__ wb1, U2* __restrict__ wb2,
                         int* __restrict__ wpcg,
                         unsigned long long* __restrict__ sums1,
                         double* __restrict__ sums2) {
    int gtid = blockIdx.x * 256 + threadIdx.x;      // 2304 jobs
    if (gtid < 256) sums1[gtid] = 0ull;
    else if (gtid < 512) sums2[gtid - 256] = 0.0;
    int tensor = gtid / 1152, rem = gtid % 1152;
    int o = rem / 9, tap = rem % 9;
    const float* w = tensor ? w2 : w1;
    unsigned long long lo = 0, hi = 0;
    for (int i = 0; i < 64; ++i)
        if (w[(o * 128 + i) * 9 + tap] > 0.f) lo |= 1ull << i;
    for (int i = 64; i < 128; ++i)
        if (w[(o * 128 + i) * 9 + tap] > 0.f) hi |= 1ull << (i - 64);
    U2 u; u.lo = lo; u.hi = hi;
    (tensor ? wb2 : wb1)[o * 9 + tap] = u;
    wpcg[gtid] = 128 - 2 * (int)(__popcll(lo) + __popcll(hi));
}

// ---------------- K0b: border-correction tables corr[o][pattern]
__global__ void k_corr(const int* __restrict__ wpcg,
                       int* __restrict__ ctab1, int* __restrict__ ctab2) {
    int gtid = blockIdx.x * 256 + threadIdx.x;      // 2304 jobs
    int tensor = gtid / 1152, rem = gtid % 1152;
    int o = rem / 9, p = rem % 9;
    int ph = p / 3, pw = p % 3;
    int c = 0;
#pragma unroll
    for (int t = 0; t < 9; ++t) {
        int kh = t / 3, kw = t % 3;
        bool inval = (ph == 1 && kh == 0) || (ph == 2 && kh == 2) ||
                     (pw == 1 && kw == 0) || (pw == 2 && kw == 2);
        if (inval) c += wpcg[tensor * 1152 + o * 9 + t];
    }
    (tensor ? ctab2 : ctab1)[o * 9 + p] = c;
}

// ---------------- K1: pack x sign bits, fully coalesced.
// thread = (channel-quarter, pixel-lane); block covers 64 consecutive pixels.
__global__ void k_pack_x(const float* __restrict__ x, U2* __restrict__ xb) {
    __shared__ unsigned sm[64][5];                  // +1 pad: conflict-free
    int tid = threadIdx.x;
    int cq = tid >> 6, pl = tid & 63;
    int P0 = blockIdx.x * 64;                       // 64 | HW so b uniform per block
    int pix = P0 + pl;
    int b = pix / HW, r = pix % HW;
    const float* base = x + ((size_t)(b * CC + cq * 32)) * HW + r;
    unsigned m = 0;
#pragma unroll
    for (int c = 0; c < 32; ++c)
        if (base[(size_t)c * HW] > 0.f) m |= 1u << c;
    sm[pl][cq] = m;
    __syncthreads();
    if (tid < 64) {
        U2 u;
        u.lo = (unsigned long long)sm[tid][0] | ((unsigned long long)sm[tid][1] << 32);
        u.hi = (unsigned long long)sm[tid][2] | ((unsigned long long)sm[tid][3] << 32);
        xb[P0 + tid] = u;
    }
}

// ---------------- K2/K4: binary conv 3x3, 4 px/thread, 8 o-channels/block.
// Weights fetched through the scalar path (block-uniform index -> s_load).
// Fused per-channel stats: RESID=0 exact int sums of y; RESID=1 double sums of y+resid.
template <int RESID>
__global__ __launch_bounds__(256)
void k_conv8(const U2* __restrict__ xb, const U2* __restrict__ wb,
             const int* __restrict__ ctab,
             short* __restrict__ yout,
             const float* __restrict__ resid, float* __restrict__ tout,
             unsigned long long* __restrict__ isums, double* __restrict__ dsums) {
    __shared__ double sW[4][8], ssW[4][8];
    __shared__ long long iW[4][8], iiW[4][8];
    int tid = threadIdx.x;
    int wid = tid >> 6, lane = tid & 63;
    int o0 = blockIdx.y * 8;
    int g = blockIdx.x * 256 + tid;                 // 4-pixel group
    int pix0 = g * 4;
    int b = pix0 / HW, r = pix0 % HW;
    int h = r / WW, w0 = r % WW;                    // groups never cross rows

    // 3x6 halo of packed bits as u32[4], zero-masked at borders
    unsigned X[3][6][4];
    const U2* xbb = xb + (size_t)b * HW;
#pragma unroll
    for (int kh = 0; kh < 3; ++kh) {
        int row = h - 1 + kh;
        bool rv = (unsigned)row < HH;
#pragma unroll
        for (int c = 0; c < 6; ++c) {
            int col = w0 - 1 + c;
            uint4 u = make_uint4(0, 0, 0, 0);
            if (rv && (unsigned)col < WW)
                u = *reinterpret_cast<const uint4*>(xbb + row * WW + col);
            X[kh][c][0] = u.x; X[kh][c][1] = u.y; X[kh][c][2] = u.z; X[kh][c][3] = u.w;
        }
    }

    int ph = (h == 0) ? 1 : ((h == HH - 1) ? 2 : 0);
    int pbase = ph * 3;
    int jspec = (w0 == 0) ? 0 : ((w0 == WW - 4) ? 3 : -1);
    int pspec = pbase + ((w0 == 0) ? 1 : 2);        // always a valid index

    size_t obase = (size_t)(b * CC + o0) * HW + r;
#pragma unroll 2
    for (int oo = 0; oo < 8; ++oo) {
        int o = o0 + oo;
        const unsigned* wp = reinterpret_cast<const unsigned*>(wb + (size_t)o * 9);
        int S0 = 0, S1 = 0, S2 = 0, S3 = 0;
#pragma unroll
        for (int t = 0; t < 9; ++t) {
            int kh = t / 3, kw = t % 3;
            unsigned wa = wp[t * 4 + 0], wbv = wp[t * 4 + 1];
            unsigned wc = wp[t * 4 + 2], wd = wp[t * 4 + 3];
            S0 += __popc(X[kh][kw + 0][0] ^ wa) + __popc(X[kh][kw + 0][1] ^ wbv)
                + __popc(X[kh][kw + 0][2] ^ wc) + __popc(X[kh][kw + 0][3] ^ wd);
            S1 += __popc(X[kh][kw + 1][0] ^ wa) + __popc(X[kh][kw + 1][1] ^ wbv)
                + __popc(X[kh][kw + 1][2] ^ wc) + __popc(X[kh][kw + 1][3] ^ wd);
            S2 += __popc(X[kh][kw + 2][0] ^ wa) + __popc(X[kh][kw + 2][1] ^ wbv)
                + __popc(X[kh][kw + 2][2] ^ wc) + __popc(X[kh][kw + 2][3] ^ wd);
            S3 += __popc(X[kh][kw + 3][0] ^ wa) + __popc(X[kh][kw + 3][1] ^ wbv)
                + __popc(X[kh][kw + 3][2] ^ wc) + __popc(X[kh][kw + 3][3] ^ wd);
        }
        int ci = ctab[o * 9 + pbase];               // 0 for interior (pattern 0)
        int cs = ctab[o * 9 + pspec];
        int c0 = (jspec == 0) ? cs : ci;
        int c3 = (jspec == 3) ? cs : ci;
        int y0 = 1152 - 2 * S0 - c0;
        int y1v = 1152 - 2 * S1 - ci;
        int y2v = 1152 - 2 * S2 - ci;
        int y3v = 1152 - 2 * S3 - c3;
        size_t idx = obase + (size_t)oo * HW;
        if (RESID) {
            float4 rv4 = *reinterpret_cast<const float4*>(resid + idx);
            float4 tv;
            tv.x = (float)y0 + rv4.x;
            tv.y = (float)y1v + rv4.y;
            tv.z = (float)y2v + rv4.z;
            tv.w = (float)y3v + rv4.w;
            *reinterpret_cast<float4*>(tout + idx) = tv;
            double s = (double)tv.x + (double)tv.y + (double)tv.z + (double)tv.w;
            double ss = (double)tv.x * tv.x + (double)tv.y * tv.y +
                        (double)tv.z * tv.z + (double)tv.w * tv.w;
#pragma unroll
            for (int d = 1; d < 64; d <<= 1) { s += __shfl_xor(s, d); ss += __shfl_xor(ss, d); }
            if (lane == 0) { sW[wid][oo] = s; ssW[wid][oo] = ss; }
        } else {
            short4 sv;
            sv.x = (short)y0; sv.y = (short)y1v; sv.z = (short)y2v; sv.w = (short)y3v;
            *reinterpret_cast<short4*>(yout + idx) = sv;
            int s = y0 + y1v + y2v + y3v;
            int ss = y0 * y0 + y1v * y1v + y2v * y2v + y3v * y3v;
#pragma unroll
            for (int d = 1; d < 64; d <<= 1) { s += __shfl_xor(s, d); ss += __shfl_xor(ss, d); }
            if (lane == 0) { iW[wid][oo] = s; iiW[wid][oo] = ss; }
        }
    }
    __syncthreads();
    if (tid < 8) {
        if (RESID) {
            double s = sW[0][tid] + sW[1][tid] + sW[2][tid] + sW[3][tid];
            double ss = ssW[0][tid] + ssW[1][tid] + ssW[2][tid] + ssW[3][tid];
            atomicAdd(&dsums[o0 + tid], s);
            atomicAdd(&dsums[128 + o0 + tid], ss);
        } else {
            long long s = iW[0][tid] + iW[1][tid] + iW[2][tid] + iW[3][tid];
            long long ss = iiW[0][tid] + iiW[1][tid] + iiW[2][tid] + iiW[3][tid];
            atomicAdd(&isums[o0 + tid], (unsigned long long)s);
            atomicAdd(&isums[128 + o0 + tid], (unsigned long long)ss);
        }
    }
}

// ---------------- K3: threshold y1 through BN1 sign and repack bits for conv2 (2 px/thread)
__global__ void k_pack2(const short* __restrict__ y1,
                        const unsigned long long* __restrict__ sums1,
                        const float* __restrict__ gamma1, const float* __restrict__ beta1,
                        U2* __restrict__ xb2) {
    __shared__ int SG[128], TA[128];
    int tid = threadIdx.x;
    if (tid < 128) {
        long long S = (long long)sums1[tid];
        long long SS = (long long)sums1[128 + tid];
        double N = (double)NPIX;
        double mean = (double)S / N;
        double var = (double)SS / N - mean * mean;
        double rr = 1.0 / sqrt(var + EPSV);
        double s = (double)gamma1[tid] * rr;
        double bb = (double)beta1[tid] - mean * s;
        int sg, A;
        if (s > 0.0) {        // bit = y > T  <=>  y > floor(T)
            double f = floor(-bb / s);
            sg = 1; A = (int)fmax(-2000.0, fmin(2000.0, f));
        } else if (s < 0.0) { // bit = y < T  <=>  -y > -ceil(T)
            double cl = ceil(-bb / s);
            sg = -1; A = -(int)fmax(-2000.0, fmin(2000.0, cl));
        } else {
            sg = 0; A = (bb > 0.0) ? -1 : 0;
        }
        SG[tid] = sg; TA[tid] = A;
    }
    __syncthreads();
    int p2 = blockIdx.x * 256 + tid;   // 2-pixel group
    int pix0 = p2 * 2;
    int b = pix0 / HW, r = pix0 % HW;
    const short* yp = y1 + (size_t)b * CC * HW + r;
    unsigned long long lo0 = 0, hi0 = 0, lo1 = 0, hi1 = 0;
#pragma unroll 8
    for (int o = 0; o < 128; ++o) {
        int v = *reinterpret_cast<const int*>(yp + (size_t)o * HW);
        int ya = (int)(short)(v & 0xffff);
        int yb = v >> 16;
        int sg = SG[o], A = TA[o];
        unsigned long long ba = (unsigned long long)(ya * sg > A);
        unsigned long long bb = (unsigned long long)(yb * sg > A);
        if (o < 64) { lo0 |= ba << o;        lo1 |= bb << o; }
        else        { hi0 |= ba << (o - 64); hi1 |= bb << (o - 64); }
    }
    U2 u;
    u.lo = lo0; u.hi = hi0; xb2[pix0] = u;
    u.lo = lo1; u.hi = hi1; xb2[pix0 + 1] = u;
}

// ---------------- K5: BN2 + hardtanh, in-place on d_out (float4)
__global__ void k_bn2(float* __restrict__ t, const double* __restrict__ sums2,
                      const float* __restrict__ gamma2, const float* __restrict__ beta2) {
    __shared__ float sA[128], bA[128];
    int tid = threadIdx.x;
    if (tid < 128) {
        double N = (double)NPIX;
        double mean = sums2[tid] / N;
        double var = sums2[128 + tid] / N - mean * mean;
        double rr = 1.0 / sqrt(var + EPSV);
        double s = (double)gamma2[tid] * rr;
        double bb = (double)beta2[tid] - mean * s;
        sA[tid] = (float)s; bA[tid] = (float)bb;
    }
    __syncthreads();
    size_t i4 = ((size_t)blockIdx.x * 256 + tid) * 4;
    int c = (int)((i4 / HW) & 127);
    float4 v = *reinterpret_cast<float4*>(t + i4);
    float s = sA[c], bb = bA[c];
    v.x = fminf(1.f, fmaxf(-1.f, v.x * s + bb));
    v.y = fminf(1.f, fmaxf(-1.f, v.y * s + bb));
    v.z = fminf(1.f, fmaxf(-1.f, v.z * s + bb));
    v.w = fminf(1.f, fmaxf(-1.f, v.w * s + bb));
    *reinterpret_cast<float4*>(t + i4) = v;
}

extern "C" void kernel_launch(void* const* d_in, const int* in_sizes, int n_in,
                              void* d_out, int out_size, void* d_ws, size_t ws_size,
                              hipStream_t stream) {
    const float* x      = (const float*)d_in[0];
    const float* w1     = (const float*)d_in[1];
    const float* w2     = (const float*)d_in[2];
    const float* gamma1 = (const float*)d_in[3];
    const float* beta1  = (const float*)d_in[4];
    const float* gamma2 = (const float*)d_in[5];
    const float* beta2  = (const float*)d_in[6];
    float* out = (float*)d_out;

    char* ws = (char*)d_ws;
    U2* wb1 = (U2*)ws;                 ws += 1152 * sizeof(U2);
    U2* wb2 = (U2*)ws;                 ws += 1152 * sizeof(U2);
    int* wpcg = (int*)ws;              ws += 2304 * sizeof(int);
    int* ctab1 = (int*)ws;             ws += 1152 * sizeof(int);
    int* ctab2 = (int*)ws;             ws += 1152 * sizeof(int);
    U2* xb  = (U2*)ws;                 ws += (size_t)NPIX * sizeof(U2);
    U2* xb2 = (U2*)ws;                 ws += (size_t)NPIX * sizeof(U2);
    short* y1 = (short*)ws;            ws += (size_t)NTOT * sizeof(short);
    unsigned long long* sums1 = (unsigned long long*)ws; ws += 256 * sizeof(unsigned long long);
    double* sums2 = (double*)ws;       ws += 256 * sizeof(double);

    k_pack_w<<<9, 256, 0, stream>>>(w1, w2, wb1, wb2, wpcg, sums1, sums2);
    k_corr<<<9, 256, 0, stream>>>(wpcg, ctab1, ctab2);
    k_pack_x<<<1568, 256, 0, stream>>>(x, xb);
    k_conv8<0><<<dim3(98, 16), 256, 0, stream>>>(xb, wb1, ctab1, y1, nullptr, nullptr, sums1, sums2);
    k_pack2<<<196, 256, 0, stream>>>(y1, sums1, gamma1, beta1, xb2);
    k_conv8<1><<<dim3(98, 16), 256, 0, stream>>>(xb2, wb2, ctab2, nullptr, x, out, sums1, sums2);
    k_bn2<<<12544, 256, 0, stream>>>(out, sums2, gamma2, beta2);
}